// Round 6
// baseline (564.387 us; speedup 1.0000x reference)
//
#include <hip/hip_runtime.h>
#include <hip/hip_bf16.h>
#include <math.h>
#include <stdint.h>

// ---------------------------------------------------------------------------
// MultiSimilarityLoss on MI355X.
//   x: [B=4096, D=1024] fp32 (L2-normalized rows), labels: [B] int32
//   out: scalar fp32 = mean of mined multi-similarity loss
// Pipeline (R7) -- 3 dispatches:
//   K1: cvt fp32->bf16, fused gmin/gmax/cnt init (block 0)
//   K2: sim = x @ x^T, FULL SQUARE 1024-block grid (4 blocks/CU exact --
//       the m97 TLP regime), BK=32 pipelined double-buffer (R6-proven core),
//       T2 swizzle. Direct C write only + row-side stats only.
//   K3: rowloss, 1 row/block x 4096 blocks, NO label LDS (L1-hot int4
//       global loads), explicit 8-load batch for MLP; fused final reduce.
// R6 post-mortem: (a) rowloss 77us @ VGPR=24: compiler serialized loads ->
//   ~2KB in flight vs ~9KB needed; LDS slab capped occupancy + 8-way bank
//   conflicts. (b) simgemm kept the 528-block triangular grid: LDS capacity
//   for 4 blocks/CU but only 2.06 supplied -- TLP fix never happened.
// ---------------------------------------------------------------------------

#define THRESH    0.5f
#define MARGIN    0.1f
#define SCALE_POS 2.0f
#define SCALE_NEG 40.0f
#define POS_CAP   (1.0f - 1e-5f)

typedef __bf16 bf16x8 __attribute__((ext_vector_type(8)));
typedef float  f32x4  __attribute__((ext_vector_type(4)));

__device__ __forceinline__ uint16_t f2bf(float f) {
  union { float f; uint32_t u; } v; v.f = f;
  uint32_t u = v.u;
  u += 0x7FFFu + ((u >> 16) & 1u);
  return (uint16_t)(u >> 16);
}

__device__ __forceinline__ uint32_t fenc(float f) {
  union { float f; uint32_t u; } v; v.f = f;
  return (v.u & 0x80000000u) ? ~v.u : (v.u ^ 0x80000000u);
}
__device__ __forceinline__ float fdec(uint32_t k) {
  union { float f; uint32_t u; } v;
  v.u = (k & 0x80000000u) ? (k ^ 0x80000000u) : ~k;
  return v.f;
}

// ---- K1: cvt + stat/counter init -------------------------------------------
__global__ __launch_bounds__(256) void cvt_bf16_kernel(
    const float* __restrict__ x, uint16_t* __restrict__ y, int n,
    uint32_t* __restrict__ gmin, uint32_t* __restrict__ gmax,
    uint32_t* __restrict__ cnt, int B) {
  const int tid = threadIdx.x;
  int i = (blockIdx.x * 256 + tid) * 4;
  if (i + 3 < n) {
    float4 v = *(const float4*)(x + i);
    ushort4 o;
    o.x = f2bf(v.x); o.y = f2bf(v.y); o.z = f2bf(v.z); o.w = f2bf(v.w);
    *(ushort4*)(y + i) = o;
  }
  if (blockIdx.x == 0) {
    for (int j = tid; j < B; j += 256) {
      gmin[j] = 0xFFFFFFFFu;
      gmax[j] = 0u;
    }
    if (tid == 0) *cnt = 0u;
  }
}

#if defined(__has_builtin)
#if __has_builtin(__builtin_amdgcn_global_load_lds)
#define HAVE_GLL 1
#endif
#endif

__device__ __forceinline__ void stage16(const uint16_t* g, uint16_t* lds_wave_base, int lane) {
#ifdef HAVE_GLL
  __builtin_amdgcn_global_load_lds(
      (const __attribute__((address_space(1))) void*)g,
      (__attribute__((address_space(3))) void*)lds_wave_base, 16, 0, 0);
#else
  *(uint4*)(lds_wave_base + lane * 8) = *(const uint4*)g;
#endif
}

// ---- K2: sim = X @ X^T, square grid, BK=32 pipelined dbuf ------------------
__global__ __launch_bounds__(256) void simgemm_kernel(
    const uint16_t* __restrict__ X, const int* __restrict__ labels,
    float* __restrict__ C, uint32_t* __restrict__ gmin, uint32_t* __restrict__ gmax,
    int B, int D) {
  // [buf][A=0/B=1][128 rows][32 cols] bf16 = 32 KiB; + 1 KiB labels = 33.8 KiB
  __shared__ __align__(16) uint16_t sT[2][2][128 * 32];
  __shared__ int slabR[128];
  __shared__ int slabC[128];

  const int nblk = B >> 7;            // 32
  const int nb   = nblk * nblk;       // 1024

  // XCD chunk swizzle (nb % 8 == 0): 128 consecutive tiles per XCD chunk
  // share 4 A-panels -> L2 locality.
  int t = blockIdx.x;
  { const int cpx = nb >> 3; t = (t & 7) * cpx + (t >> 3); }
  const int bi = t / nblk;
  const int bj = t - bi * nblk;
  const int bm = bi * 128;
  const int bn = bj * 128;

  const int tid  = threadIdx.x;
  const int wave = tid >> 6;
  const int lane = tid & 63;
  const int waveM = wave >> 1, waveN = wave & 1;

  if (tid < 128) slabR[tid] = labels[bm + tid];
  else           slabC[tid - 128] = labels[bn + tid - 128];

  const uint16_t* gA = X + (size_t)bm * D;
  const uint16_t* gB = X + (size_t)bn * D;

  // staging map: 16B-chunk idx = s*256 + tid (s=0,1); row = idx>>2 (64B rows)
  // inverse-swizzled global byte-in-row = ((idx&3)<<4) ^ ((row&3)<<4)
  int srcOff[2];
#pragma unroll
  for (int s = 0; s < 2; ++s) {
    const int idx = s * 256 + tid;
    const int row = idx >> 2;
    const int cb  = ((idx & 3) << 4) ^ ((row & 3) << 4);
    srcOff[s] = row * D + (cb >> 1);
  }

  const int fr = lane & 15;
  const int fq = lane >> 4;
  const int sw = (fr & 3) << 4;   // read swizzle (row&3 == fr&3)

  f32x4 acc[4][4] = {};

  const int NT = D >> 5;          // 32 K-tiles of 32

  // prologue: stage tile 0 into buf 0
#pragma unroll
  for (int s = 0; s < 2; ++s) {
    uint16_t* dA = &sT[0][0][0] + (s * 256 + wave * 64) * 8;
    uint16_t* dB = &sT[0][1][0] + (s * 256 + wave * 64) * 8;
    stage16(gA + srcOff[s], dA, lane);
    stage16(gB + srcOff[s], dB, lane);
  }
  __syncthreads();

  int cur = 0;
  for (int kt = 0; kt < NT; ++kt) {
    if (kt + 1 < NT) {
      const int k0 = (kt + 1) << 5;
#pragma unroll
      for (int s = 0; s < 2; ++s) {
        uint16_t* dA = &sT[cur ^ 1][0][0] + (s * 256 + wave * 64) * 8;
        uint16_t* dB = &sT[cur ^ 1][1][0] + (s * 256 + wave * 64) * 8;
        stage16(gA + srcOff[s] + k0, dA, lane);
        stage16(gB + srcOff[s] + k0, dB, lane);
      }
    }

    const char* tA = (const char*)&sT[cur][0][0];
    const char* tB = (const char*)&sT[cur][1][0];
    const int cbyte = (fq * 16) ^ sw;
    bf16x8 af[4], bfv[4];
#pragma unroll
    for (int mt = 0; mt < 4; ++mt) {
      const int rowa = waveM * 64 + mt * 16 + fr;
      af[mt] = *(const bf16x8*)(tA + rowa * 64 + cbyte);
    }
#pragma unroll
    for (int nt = 0; nt < 4; ++nt) {
      const int rowb = waveN * 64 + nt * 16 + fr;
      bfv[nt] = *(const bf16x8*)(tB + rowb * 64 + cbyte);
    }
#pragma unroll
    for (int mt = 0; mt < 4; ++mt)
#pragma unroll
      for (int nt = 0; nt < 4; ++nt)
        acc[mt][nt] = __builtin_amdgcn_mfma_f32_16x16x32_bf16(
            af[mt], bfv[nt], acc[mt][nt], 0, 0, 0);

    __syncthreads();
    cur ^= 1;
  }

  // ---- direct write C[bm..][bn..] (only write; square grid covers all) ----
#pragma unroll
  for (int mt = 0; mt < 4; ++mt) {
#pragma unroll
    for (int nt = 0; nt < 4; ++nt) {
      const int col = bn + waveN * 64 + nt * 16 + fr;
#pragma unroll
      for (int r = 0; r < 4; ++r) {
        const int row = bm + waveM * 64 + mt * 16 + fq * 4 + r;
        C[(size_t)row * B + col] = acc[mt][nt][r];
      }
    }
  }

  // ---- per-row stats: min positive (valid), max negative (row-side only) --
  const float INF = __builtin_inff();

  int lr[4][4];
#pragma unroll
  for (int mt = 0; mt < 4; ++mt)
#pragma unroll
    for (int r = 0; r < 4; ++r)
      lr[mt][r] = slabR[waveM * 64 + mt * 16 + fq * 4 + r];
  int lc[4];
#pragma unroll
  for (int nt = 0; nt < 4; ++nt) lc[nt] = slabC[waveN * 64 + nt * 16 + fr];

  float rmin[4][4], rmax[4][4];
#pragma unroll
  for (int mt = 0; mt < 4; ++mt)
#pragma unroll
    for (int r = 0; r < 4; ++r) { rmin[mt][r] = INF; rmax[mt][r] = -INF; }

#pragma unroll
  for (int mt = 0; mt < 4; ++mt) {
#pragma unroll
    for (int nt = 0; nt < 4; ++nt) {
      const int gcol = bn + waveN * 64 + nt * 16 + fr;
#pragma unroll
      for (int r = 0; r < 4; ++r) {
        const int grow = bm + waveM * 64 + mt * 16 + fq * 4 + r;
        const float s = acc[mt][nt][r];
        if (lr[mt][r] == lc[nt]) {
          if (grow != gcol && s < POS_CAP) rmin[mt][r] = fminf(rmin[mt][r], s);
        } else {
          rmax[mt][r] = fmaxf(rmax[mt][r], s);
        }
      }
    }
  }
#pragma unroll
  for (int mt = 0; mt < 4; ++mt)
#pragma unroll
    for (int r = 0; r < 4; ++r) {
#pragma unroll
      for (int m = 1; m < 16; m <<= 1) {
        rmin[mt][r] = fminf(rmin[mt][r], __shfl_xor(rmin[mt][r], m, 64));
        rmax[mt][r] = fmaxf(rmax[mt][r], __shfl_xor(rmax[mt][r], m, 64));
      }
    }
  if (fr == 0) {
#pragma unroll
    for (int mt = 0; mt < 4; ++mt)
#pragma unroll
      for (int r = 0; r < 4; ++r) {
        const int grow = bm + waveM * 64 + mt * 16 + fq * 4 + r;
        if (rmin[mt][r] < INF)  atomicMin(&gmin[grow], fenc(rmin[mt][r]));
        if (rmax[mt][r] > -INF) atomicMax(&gmax[grow], fenc(rmax[mt][r]));
      }
  }
}

// ---- K3: rowloss, 1 row/block, no LDS slab, explicit 8-load batches --------
__device__ __forceinline__ void proc4(
    const float4 v, const int4 lb, int jbase, int i, int li,
    float minpos, float maxneg, float& ps, float& ns) {
  const float s4[4] = {v.x, v.y, v.z, v.w};
  const int   l4[4] = {lb.x, lb.y, lb.z, lb.w};
#pragma unroll
  for (int q = 0; q < 4; ++q) {
    const int jj = jbase + q;
    const float s = s4[q];
    if (l4[q] == li) {
      if (jj != i && s < POS_CAP && (s - MARGIN < maxneg))
        ps += __expf(-SCALE_POS * (s - THRESH));
    } else {
      if (s + MARGIN > minpos)
        ns += __expf(SCALE_NEG * (s - THRESH));
    }
  }
}

__global__ __launch_bounds__(256) void rowloss_kernel(
    const float* __restrict__ sim, const int* __restrict__ labels,
    const uint32_t* __restrict__ gmin, const uint32_t* __restrict__ gmax,
    float* __restrict__ rowbuf, float* __restrict__ out,
    uint32_t* __restrict__ cnt, int B) {
  __shared__ float red[8];
  __shared__ float fred[4];
  __shared__ int   isLast;

  const int tid  = threadIdx.x;
  const int wave = tid >> 6;
  const int lane = tid & 63;
  const float INF = __builtin_inff();

  const int i = blockIdx.x;
  const int li = labels[i];
  const uint32_t km = gmin[i], kx = gmax[i];
  const bool haspos = (km != 0xFFFFFFFFu);
  const bool hasneg = (kx != 0u);
  const float minpos = haspos ? fdec(km) : INF;
  const float maxneg = hasneg ? fdec(kx) : -INF;
  const float* row = sim + (size_t)i * B;

  float ps = 0.f, ns = 0.f;
  // B % 4096 == 0 (problem shape): 4 sim-float4 + 4 label-int4 issued
  // back-to-back per batch -> 8 loads in flight per thread (MLP).
  for (int j0 = 0; j0 < B; j0 += 4096) {
    const int jb = j0 + tid * 4;
    const float4 v0 = *(const float4*)(row + jb);
    const float4 v1 = *(const float4*)(row + jb + 1024);
    const float4 v2 = *(const float4*)(row + jb + 2048);
    const float4 v3 = *(const float4*)(row + jb + 3072);
    const int4   l0 = *(const int4*)(labels + jb);
    const int4   l1 = *(const int4*)(labels + jb + 1024);
    const int4   l2 = *(const int4*)(labels + jb + 2048);
    const int4   l3 = *(const int4*)(labels + jb + 3072);
    proc4(v0, l0, jb,        i, li, minpos, maxneg, ps, ns);
    proc4(v1, l1, jb + 1024, i, li, minpos, maxneg, ps, ns);
    proc4(v2, l2, jb + 2048, i, li, minpos, maxneg, ps, ns);
    proc4(v3, l3, jb + 3072, i, li, minpos, maxneg, ps, ns);
  }

#pragma unroll
  for (int m = 32; m > 0; m >>= 1) {
    ps += __shfl_xor(ps, m, 64);
    ns += __shfl_xor(ns, m, 64);
  }
  if (lane == 0) { red[wave] = ps; red[4 + wave] = ns; }
  __syncthreads();

  if (tid == 0) {
    const float P = red[0] + red[1] + red[2] + red[3];
    const float N = red[4] + red[5] + red[6] + red[7];
    const bool has_row = haspos && hasneg && (P > 0.f) && (N > 0.f);
    rowbuf[i] = has_row
        ? (log1pf(P) * (1.0f / SCALE_POS) + log1pf(N) * (1.0f / SCALE_NEG))
        : 0.f;
  }
  __threadfence();
  __syncthreads();

  if (tid == 0) {
    const uint32_t v = atomicAdd(cnt, 1u);
    isLast = (v == (uint32_t)(gridDim.x - 1)) ? 1 : 0;
  }
  __syncthreads();

  if (isLast) {
    __threadfence();
    float s = 0.f;
    for (int j = tid * 4; j < B; j += 1024) {
      float4 v = *(const float4*)(rowbuf + j);
      s += v.x + v.y + v.z + v.w;
    }
#pragma unroll
    for (int m = 32; m > 0; m >>= 1) s += __shfl_xor(s, m, 64);
    if (lane == 0) fred[wave] = s;
    __syncthreads();
    if (tid == 0)
      out[0] = (fred[0] + fred[1] + fred[2] + fred[3]) * (1.0f / (float)B);
  }
}

// ---------------------------------------------------------------------------
extern "C" void kernel_launch(void* const* d_in, const int* in_sizes, int n_in,
                              void* d_out, int out_size, void* d_ws, size_t ws_size,
                              hipStream_t stream) {
  const float* x      = (const float*)d_in[0];
  const int*   labels = (const int*)d_in[1];
  float*       out    = (float*)d_out;

  const int B = in_sizes[1];           // 4096
  const int D = in_sizes[0] / B;       // 1024

  char* ws = (char*)d_ws;
  uint16_t* xbf = (uint16_t*)ws;       ws += (((size_t)B * D * 2) + 255) & ~(size_t)255;
  float* sim = (float*)ws;             ws += (size_t)B * B * 4;
  uint32_t* gmin = (uint32_t*)ws;      ws += (size_t)B * 4;
  uint32_t* gmax = (uint32_t*)ws;      ws += (size_t)B * 4;
  float* rowbuf = (float*)ws;          ws += (size_t)B * 4;
  uint32_t* cnt = (uint32_t*)ws;       ws += 256;

  const int n = B * D;
  cvt_bf16_kernel<<<n / 1024, 256, 0, stream>>>(x, xbf, n, gmin, gmax, cnt, B);

  const int nblk = B / 128;
  const int nb   = nblk * nblk;        // 1024 square tiles = 4 blocks/CU
  simgemm_kernel<<<nb, 256, 0, stream>>>(xbf, labels, sim, gmin, gmax, B, D);

  rowloss_kernel<<<B, 256, 0, stream>>>(sim, labels, gmin, gmax,
                                        rowbuf, out, cnt, B);
}

// Round 8
// 278.416 us; speedup vs baseline: 2.0271x; 2.0271x over previous
//
#include <hip/hip_runtime.h>
#include <hip/hip_bf16.h>
#include <math.h>
#include <stdint.h>

// ---------------------------------------------------------------------------
// MultiSimilarityLoss on MI355X.
//   x: [B=4096, D=1024] fp32 (L2-normalized rows), labels: [B] int32
//   out: scalar fp32 = mean of mined multi-similarity loss
// Pipeline (R8, resubmitted after infra failure) -- 3 dispatches:
//   K1: cvt fp32->bf16, fused gmin/gmax/cnt init (block 0)
//   K2: sim = x @ x^T -- EXACT R3 GEMM (measured 66us, best of 6 rounds):
//       528 upper-tri 128x128 tiles, BK=64 double-buffer 2-phase prefetch,
//       T2 both-sides swizzle, mirror write, fused row+col stats.
//   K3: rowloss: 2 rows/block x 2048 blocks (8 blocks/CU, 32 waves/CU),
//       sim rows staged via global_load_lds DOUBLE-BUFFER (zero VGPR for
//       in-flight data -> cannot spill, cannot be un-hoisted), predicated
//       per-element math, fused last-block final reduce.
// R7 post-mortem: explicit 8-load batch spilled (VGPR=32 cap chosen by
//   compiler -> 45MB scratch writes, 428us). gll staging is the spill-proof
//   way to get MLP. R6/R7 BK=32 GEMMs also lost to R3's BK=64 (66us).
// ---------------------------------------------------------------------------

#define THRESH    0.5f
#define MARGIN    0.1f
#define SCALE_POS 2.0f
#define SCALE_NEG 40.0f
#define POS_CAP   (1.0f - 1e-5f)

typedef __bf16 bf16x8 __attribute__((ext_vector_type(8)));
typedef float  f32x4  __attribute__((ext_vector_type(4)));

__device__ __forceinline__ uint16_t f2bf(float f) {
  union { float f; uint32_t u; } v; v.f = f;
  uint32_t u = v.u;
  u += 0x7FFFu + ((u >> 16) & 1u);
  return (uint16_t)(u >> 16);
}

__device__ __forceinline__ uint32_t fenc(float f) {
  union { float f; uint32_t u; } v; v.f = f;
  return (v.u & 0x80000000u) ? ~v.u : (v.u ^ 0x80000000u);
}
__device__ __forceinline__ float fdec(uint32_t k) {
  union { float f; uint32_t u; } v;
  v.u = (k & 0x80000000u) ? (k ^ 0x80000000u) : ~k;
  return v.f;
}

// ---- K1: cvt + stat/counter init -------------------------------------------
__global__ __launch_bounds__(256) void cvt_bf16_kernel(
    const float* __restrict__ x, uint16_t* __restrict__ y, int n,
    uint32_t* __restrict__ gmin, uint32_t* __restrict__ gmax,
    uint32_t* __restrict__ cnt, int B) {
  const int tid = threadIdx.x;
  int i = (blockIdx.x * 256 + tid) * 4;
  if (i + 3 < n) {
    float4 v = *(const float4*)(x + i);
    ushort4 o;
    o.x = f2bf(v.x); o.y = f2bf(v.y); o.z = f2bf(v.z); o.w = f2bf(v.w);
    *(ushort4*)(y + i) = o;
  }
  if (blockIdx.x == 0) {
    for (int j = tid; j < B; j += 256) {
      gmin[j] = 0xFFFFFFFFu;
      gmax[j] = 0u;
    }
    if (tid == 0) *cnt = 0u;
  }
}

#if defined(__has_builtin)
#if __has_builtin(__builtin_amdgcn_global_load_lds)
#define HAVE_GLL 1
#endif
#endif

__device__ __forceinline__ void stage16(const uint16_t* g, uint16_t* lds_wave_base, int lane) {
#ifdef HAVE_GLL
  __builtin_amdgcn_global_load_lds(
      (const __attribute__((address_space(1))) void*)g,
      (__attribute__((address_space(3))) void*)lds_wave_base, 16, 0, 0);
#else
  *(uint4*)(lds_wave_base + lane * 8) = *(const uint4*)g;
#endif
}

// ---- K2: sim = X @ X^T, upper-tri 128x128 tiles, BK=64, 2-phase dbuf -------
// EXACT R3 kernel (measured 66us, 0 bank conflicts). Do not touch.
__global__ __launch_bounds__(256) void simgemm_kernel(
    const uint16_t* __restrict__ X, const int* __restrict__ labels,
    float* __restrict__ C, uint32_t* __restrict__ gmin, uint32_t* __restrict__ gmax,
    int B, int D) {
  __shared__ __align__(16) uint16_t sT[2][2][128 * 64];
  __shared__ int slabR[128];
  __shared__ int slabC[128];

  const int nblk = B >> 7;
  const int nb   = nblk * (nblk + 1) / 2;

  int t = blockIdx.x;
  if ((nb & 7) == 0) {
    const int cpx = nb >> 3;
    t = (t % 8) * cpx + t / 8;
  }
  int bi = 0;
  while (t >= nblk - bi) { t -= nblk - bi; ++bi; }
  const int bj = bi + t;
  const int bm = bi * 128;
  const int bn = bj * 128;

  const int tid  = threadIdx.x;
  const int wave = tid >> 6;
  const int lane = tid & 63;
  const int waveM = wave >> 1, waveN = wave & 1;

  if (tid < 128) slabR[tid] = labels[bm + tid];
  else           slabC[tid - 128] = labels[bn + tid - 128];

  const uint16_t* gA = X + (size_t)bm * D;
  const uint16_t* gB = X + (size_t)bn * D;

  int srcOff[4];
#pragma unroll
  for (int s = 0; s < 4; ++s) {
    const int idx = s * 256 + tid;
    const int row = idx >> 3;
    const int cb  = ((idx & 7) << 4) ^ ((row & 7) << 4);
    srcOff[s] = row * D + (cb >> 1);
  }

  const int fr = lane & 15;
  const int fq = lane >> 4;
  const int sw = (fr & 7) << 4;

  f32x4 acc[4][4] = {};

  const int NT = D >> 6;

#pragma unroll
  for (int s = 0; s < 4; ++s) {
    uint16_t* dA = &sT[0][0][0] + (s * 256 + wave * 64) * 8;
    uint16_t* dB = &sT[0][1][0] + (s * 256 + wave * 64) * 8;
    stage16(gA + srcOff[s], dA, lane);
    stage16(gB + srcOff[s], dB, lane);
  }
  __syncthreads();

  int cur = 0;
  for (int kt = 0; kt < NT; ++kt) {
    if (kt + 1 < NT) {
      const int k0 = (kt + 1) << 6;
#pragma unroll
      for (int s = 0; s < 4; ++s) {
        uint16_t* dA = &sT[cur ^ 1][0][0] + (s * 256 + wave * 64) * 8;
        uint16_t* dB = &sT[cur ^ 1][1][0] + (s * 256 + wave * 64) * 8;
        stage16(gA + srcOff[s] + k0, dA, lane);
        stage16(gB + srcOff[s] + k0, dB, lane);
      }
    }

    const char* tA = (const char*)&sT[cur][0][0];
    const char* tB = (const char*)&sT[cur][1][0];
#pragma unroll
    for (int kk = 0; kk < 2; ++kk) {
      const int cbyte = (kk * 64 + fq * 16) ^ sw;
      bf16x8 af[4], bfv[4];
#pragma unroll
      for (int mt = 0; mt < 4; ++mt) {
        const int rowa = waveM * 64 + mt * 16 + fr;
        af[mt] = *(const bf16x8*)(tA + rowa * 128 + cbyte);
      }
#pragma unroll
      for (int nt = 0; nt < 4; ++nt) {
        const int rowb = waveN * 64 + nt * 16 + fr;
        bfv[nt] = *(const bf16x8*)(tB + rowb * 128 + cbyte);
      }
#pragma unroll
      for (int mt = 0; mt < 4; ++mt)
#pragma unroll
        for (int nt = 0; nt < 4; ++nt)
          acc[mt][nt] = __builtin_amdgcn_mfma_f32_16x16x32_bf16(
              af[mt], bfv[nt], acc[mt][nt], 0, 0, 0);
    }

    __syncthreads();
    cur ^= 1;
  }

  // direct write
#pragma unroll
  for (int mt = 0; mt < 4; ++mt) {
#pragma unroll
    for (int nt = 0; nt < 4; ++nt) {
      const int col = bn + waveN * 64 + nt * 16 + fr;
#pragma unroll
      for (int r = 0; r < 4; ++r) {
        const int row = bm + waveM * 64 + mt * 16 + fq * 4 + r;
        C[(size_t)row * B + col] = acc[mt][nt][r];
      }
    }
  }

  // mirror write
  if (bi != bj) {
#pragma unroll
    for (int mt = 0; mt < 4; ++mt) {
#pragma unroll
      for (int nt = 0; nt < 4; ++nt) {
        const int col  = bn + waveN * 64 + nt * 16 + fr;
        const int rowb = bm + waveM * 64 + mt * 16 + fq * 4;
        *(f32x4*)(C + (size_t)col * B + rowb) = acc[mt][nt];
      }
    }
  }

  const float INF = __builtin_inff();

  int lr[4][4];
#pragma unroll
  for (int mt = 0; mt < 4; ++mt)
#pragma unroll
    for (int r = 0; r < 4; ++r)
      lr[mt][r] = slabR[waveM * 64 + mt * 16 + fq * 4 + r];
  int lc[4];
#pragma unroll
  for (int nt = 0; nt < 4; ++nt) lc[nt] = slabC[waveN * 64 + nt * 16 + fr];

  // row-side stats
  {
    float rmin[4][4], rmax[4][4];
#pragma unroll
    for (int mt = 0; mt < 4; ++mt)
#pragma unroll
      for (int r = 0; r < 4; ++r) { rmin[mt][r] = INF; rmax[mt][r] = -INF; }

#pragma unroll
    for (int mt = 0; mt < 4; ++mt) {
#pragma unroll
      for (int nt = 0; nt < 4; ++nt) {
        const int gcol = bn + waveN * 64 + nt * 16 + fr;
#pragma unroll
        for (int r = 0; r < 4; ++r) {
          const int grow = bm + waveM * 64 + mt * 16 + fq * 4 + r;
          const float s = acc[mt][nt][r];
          if (lr[mt][r] == lc[nt]) {
            if (grow != gcol && s < POS_CAP) rmin[mt][r] = fminf(rmin[mt][r], s);
          } else {
            rmax[mt][r] = fmaxf(rmax[mt][r], s);
          }
        }
      }
    }
#pragma unroll
    for (int mt = 0; mt < 4; ++mt)
#pragma unroll
      for (int r = 0; r < 4; ++r) {
#pragma unroll
        for (int m = 1; m < 16; m <<= 1) {
          rmin[mt][r] = fminf(rmin[mt][r], __shfl_xor(rmin[mt][r], m, 64));
          rmax[mt][r] = fmaxf(rmax[mt][r], __shfl_xor(rmax[mt][r], m, 64));
        }
      }
    if (fr == 0) {
#pragma unroll
      for (int mt = 0; mt < 4; ++mt)
#pragma unroll
        for (int r = 0; r < 4; ++r) {
          const int grow = bm + waveM * 64 + mt * 16 + fq * 4 + r;
          if (rmin[mt][r] < INF)  atomicMin(&gmin[grow], fenc(rmin[mt][r]));
          if (rmax[mt][r] > -INF) atomicMax(&gmax[grow], fenc(rmax[mt][r]));
        }
    }
  }

  // col-side stats (mirrored tile)
  if (bi != bj) {
    float cmin[4], cmax[4];
#pragma unroll
    for (int nt = 0; nt < 4; ++nt) { cmin[nt] = INF; cmax[nt] = -INF; }
#pragma unroll
    for (int nt = 0; nt < 4; ++nt) {
      const int gcol = bn + waveN * 64 + nt * 16 + fr;
#pragma unroll
      for (int mt = 0; mt < 4; ++mt) {
#pragma unroll
        for (int r = 0; r < 4; ++r) {
          const int grow = bm + waveM * 64 + mt * 16 + fq * 4 + r;
          const float s = acc[mt][nt][r];
          if (lc[nt] == lr[mt][r]) {
            if (grow != gcol && s < POS_CAP) cmin[nt] = fminf(cmin[nt], s);
          } else {
            cmax[nt] = fmaxf(cmax[nt], s);
          }
        }
      }
    }
#pragma unroll
    for (int nt = 0; nt < 4; ++nt) {
#pragma unroll
      for (int m = 16; m < 64; m <<= 1) {
        cmin[nt] = fminf(cmin[nt], __shfl_xor(cmin[nt], m, 64));
        cmax[nt] = fmaxf(cmax[nt], __shfl_xor(cmax[nt], m, 64));
      }
    }
    if (fq == 0) {
#pragma unroll
      for (int nt = 0; nt < 4; ++nt) {
        const int gcol = bn + waveN * 64 + nt * 16 + fr;
        if (cmin[nt] < INF)  atomicMin(&gmin[gcol], fenc(cmin[nt]));
        if (cmax[nt] > -INF) atomicMax(&gmax[gcol], fenc(cmax[nt]));
      }
    }
  }
}

// ---- K3: rowloss, 2 rows/block, gll-staged dbuf, fused final reduce --------
__device__ __forceinline__ void proc4p(
    const float4 v, const int4 lb, int jbase, int i, int li,
    float minpos, float maxneg, float& ps, float& ns) {
  const float s4[4] = {v.x, v.y, v.z, v.w};
  const int   l4[4] = {lb.x, lb.y, lb.z, lb.w};
#pragma unroll
  for (int q = 0; q < 4; ++q) {
    const int jj = jbase + q;
    const float s = s4[q];
    const bool same = (l4[q] == li);
    const bool pk = same && (jj != i) && (s < POS_CAP) && (s - MARGIN < maxneg);
    const bool nk = (!same) && (s + MARGIN > minpos);
    // predicated: exp is cheap (trans pipe), cndmask keeps lanes convergent
    const float ep = __expf(-SCALE_POS * (s - THRESH));
    const float en = __expf( SCALE_NEG * (s - THRESH));
    ps += pk ? ep : 0.f;
    ns += nk ? en : 0.f;
  }
}

__global__ __launch_bounds__(256) void rowloss_kernel(
    const float* __restrict__ sim, const int* __restrict__ labels,
    const uint32_t* __restrict__ gmin, const uint32_t* __restrict__ gmax,
    float* __restrict__ rowbuf, float* __restrict__ out,
    uint32_t* __restrict__ cnt, int B) {
  // [dbuf][row][1024 floats] = 16 KiB -> 8 blocks/CU (32 waves/CU)
  __shared__ __align__(16) float sbuf[2][2][1024];
  __shared__ float red[4][4];
  __shared__ float fred[4];
  __shared__ int   isLast;

  const int tid  = threadIdx.x;
  const int wave = tid >> 6;
  const int lane = tid & 63;
  const float INF = __builtin_inff();

  const int i0 = blockIdx.x * 2;
  const int li0 = labels[i0];
  const int li1 = labels[i0 + 1];

  const uint32_t km0 = gmin[i0],     kx0 = gmax[i0];
  const uint32_t km1 = gmin[i0 + 1], kx1 = gmax[i0 + 1];
  const bool hp0 = (km0 != 0xFFFFFFFFu), hn0 = (kx0 != 0u);
  const bool hp1 = (km1 != 0xFFFFFFFFu), hn1 = (kx1 != 0u);
  const float mp0 = hp0 ? fdec(km0) : INF,  mx0 = hn0 ? fdec(kx0) : -INF;
  const float mp1 = hp1 ? fdec(km1) : INF,  mx1 = hn1 ? fdec(kx1) : -INF;

  const float* row0 = sim + (size_t)i0 * B;
  const float* row1 = row0 + B;

  const int NC = B >> 10;        // 1024-col chunks (4 for B=4096)

  // prologue: stage chunk 0 (both rows) into buf 0. gll: src per-lane,
  // dest wave-uniform base + lane*16 -> zero VGPRs hold in-flight data.
  {
    const uint16_t* g0 = (const uint16_t*)(row0 + tid * 4);
    const uint16_t* g1 = (const uint16_t*)(row1 + tid * 4);
    stage16(g0, (uint16_t*)&sbuf[0][0][wave * 256], lane);
    stage16(g1, (uint16_t*)&sbuf[0][1][wave * 256], lane);
  }

  float ps0 = 0.f, ns0 = 0.f, ps1 = 0.f, ns1 = 0.f;
  int buf = 0;
  for (int c = 0; c < NC; ++c) {
    __syncthreads();             // drains gll for chunk c (vmcnt) + LDS reads
    if (c + 1 < NC) {            // prefetch c+1; latency hides under proc
      const int jn = (c + 1) << 10;
      const uint16_t* g0 = (const uint16_t*)(row0 + jn + tid * 4);
      const uint16_t* g1 = (const uint16_t*)(row1 + jn + tid * 4);
      stage16(g0, (uint16_t*)&sbuf[buf ^ 1][0][wave * 256], lane);
      stage16(g1, (uint16_t*)&sbuf[buf ^ 1][1][wave * 256], lane);
    }
    const int jb = (c << 10) + tid * 4;
    const int4 lb = *(const int4*)(labels + jb);
    const float4 v0 = *(const float4*)(&sbuf[buf][0][tid * 4]);
    const float4 v1 = *(const float4*)(&sbuf[buf][1][tid * 4]);
    proc4p(v0, lb, jb, i0,     li0, mp0, mx0, ps0, ns0);
    proc4p(v1, lb, jb, i0 + 1, li1, mp1, mx1, ps1, ns1);
    buf ^= 1;
  }

#pragma unroll
  for (int m = 32; m > 0; m >>= 1) {
    ps0 += __shfl_xor(ps0, m, 64);
    ns0 += __shfl_xor(ns0, m, 64);
    ps1 += __shfl_xor(ps1, m, 64);
    ns1 += __shfl_xor(ns1, m, 64);
  }
  if (lane == 0) {
    red[wave][0] = ps0; red[wave][1] = ns0;
    red[wave][2] = ps1; red[wave][3] = ns1;
  }
  __syncthreads();

  if (tid < 2) {
    const int r = tid;
    const float P = red[0][r * 2] + red[1][r * 2] + red[2][r * 2] + red[3][r * 2];
    const float N = red[0][r * 2 + 1] + red[1][r * 2 + 1] + red[2][r * 2 + 1] + red[3][r * 2 + 1];
    const bool hp = r ? hp1 : hp0;
    const bool hn = r ? hn1 : hn0;
    const bool has_row = hp && hn && (P > 0.f) && (N > 0.f);
    rowbuf[i0 + r] = has_row
        ? (log1pf(P) * (1.0f / SCALE_POS) + log1pf(N) * (1.0f / SCALE_NEG))
        : 0.f;
  }
  __threadfence();
  __syncthreads();

  if (tid == 0) {
    const uint32_t v = atomicAdd(cnt, 1u);
    isLast = (v == (uint32_t)(gridDim.x - 1)) ? 1 : 0;
  }
  __syncthreads();

  if (isLast) {
    __threadfence();
    float s = 0.f;
    for (int j = tid * 4; j < B; j += 1024) {
      float4 v = *(const float4*)(rowbuf + j);
      s += v.x + v.y + v.z + v.w;
    }
#pragma unroll
    for (int m = 32; m > 0; m >>= 1) s += __shfl_xor(s, m, 64);
    if (lane == 0) fred[wave] = s;
    __syncthreads();
    if (tid == 0)
      out[0] = (fred[0] + fred[1] + fred[2] + fred[3]) * (1.0f / (float)B);
  }
}

// ---------------------------------------------------------------------------
extern "C" void kernel_launch(void* const* d_in, const int* in_sizes, int n_in,
                              void* d_out, int out_size, void* d_ws, size_t ws_size,
                              hipStream_t stream) {
  const float* x      = (const float*)d_in[0];
  const int*   labels = (const int*)d_in[1];
  float*       out    = (float*)d_out;

  const int B = in_sizes[1];           // 4096
  const int D = in_sizes[0] / B;       // 1024

  char* ws = (char*)d_ws;
  uint16_t* xbf = (uint16_t*)ws;       ws += (((size_t)B * D * 2) + 255) & ~(size_t)255;
  float* sim = (float*)ws;             ws += (size_t)B * B * 4;
  uint32_t* gmin = (uint32_t*)ws;      ws += (size_t)B * 4;
  uint32_t* gmax = (uint32_t*)ws;      ws += (size_t)B * 4;
  float* rowbuf = (float*)ws;          ws += (size_t)B * 4;
  uint32_t* cnt = (uint32_t*)ws;       ws += 256;

  const int n = B * D;
  cvt_bf16_kernel<<<n / 1024, 256, 0, stream>>>(x, xbf, n, gmin, gmax, cnt, B);

  const int nblk = B / 128;
  const int nb   = nblk * (nblk + 1) / 2;   // 528 upper-triangle tiles
  simgemm_kernel<<<nb, 256, 0, stream>>>(xbf, labels, sim, gmin, gmax, B, D);

  rowloss_kernel<<<B / 2, 256, 0, stream>>>(sim, labels, gmin, gmax,
                                            rowbuf, out, cnt, B);
}

// Round 9
// 274.162 us; speedup vs baseline: 2.0586x; 1.0155x over previous
//
#include <hip/hip_runtime.h>
#include <hip/hip_bf16.h>
#include <math.h>
#include <stdint.h>

// ---------------------------------------------------------------------------
// MultiSimilarityLoss on MI355X.
//   x: [B=4096, D=1024] fp32 (L2-normalized rows), labels: [B] int32
//   out: scalar fp32 = mean of mined multi-similarity loss
// Pipeline (R9) -- 3 dispatches:
//   K1: cvt fp32->bf16, fused gmin/gmax/cnt init (block 0)
//   K2: sim = x @ x^T -- EXACT R3 GEMM (measured 66us). Untouched.
//   K3: rowloss: 2 rows/block x 2048 blocks; sim chunks AND label chunks
//       both staged via global_load_lds double-buffer. ZERO non-gll vmem
//       in the loop -> no in-order-vmcnt serialization (R8's bug: labels
//       global-load issued after prefetch glls forced vmcnt(0) per iter,
//       putting gll latency on the critical path every chunk).
//       Labels read from LDS as int4 ds_read_b128 (conflict-free; R6's
//       393K conflicts were from SCALAR slab[jj] reads, not b128).
//       Fused last-block final reduce.
// ---------------------------------------------------------------------------

#define THRESH    0.5f
#define MARGIN    0.1f
#define SCALE_POS 2.0f
#define SCALE_NEG 40.0f
#define POS_CAP   (1.0f - 1e-5f)

typedef __bf16 bf16x8 __attribute__((ext_vector_type(8)));
typedef float  f32x4  __attribute__((ext_vector_type(4)));

__device__ __forceinline__ uint16_t f2bf(float f) {
  union { float f; uint32_t u; } v; v.f = f;
  uint32_t u = v.u;
  u += 0x7FFFu + ((u >> 16) & 1u);
  return (uint16_t)(u >> 16);
}

__device__ __forceinline__ uint32_t fenc(float f) {
  union { float f; uint32_t u; } v; v.f = f;
  return (v.u & 0x80000000u) ? ~v.u : (v.u ^ 0x80000000u);
}
__device__ __forceinline__ float fdec(uint32_t k) {
  union { float f; uint32_t u; } v;
  v.u = (k & 0x80000000u) ? (k ^ 0x80000000u) : ~k;
  return v.f;
}

// ---- K1: cvt + stat/counter init -------------------------------------------
__global__ __launch_bounds__(256) void cvt_bf16_kernel(
    const float* __restrict__ x, uint16_t* __restrict__ y, int n,
    uint32_t* __restrict__ gmin, uint32_t* __restrict__ gmax,
    uint32_t* __restrict__ cnt, int B) {
  const int tid = threadIdx.x;
  int i = (blockIdx.x * 256 + tid) * 4;
  if (i + 3 < n) {
    float4 v = *(const float4*)(x + i);
    ushort4 o;
    o.x = f2bf(v.x); o.y = f2bf(v.y); o.z = f2bf(v.z); o.w = f2bf(v.w);
    *(ushort4*)(y + i) = o;
  }
  if (blockIdx.x == 0) {
    for (int j = tid; j < B; j += 256) {
      gmin[j] = 0xFFFFFFFFu;
      gmax[j] = 0u;
    }
    if (tid == 0) *cnt = 0u;
  }
}

#if defined(__has_builtin)
#if __has_builtin(__builtin_amdgcn_global_load_lds)
#define HAVE_GLL 1
#endif
#endif

__device__ __forceinline__ void stage16(const uint16_t* g, uint16_t* lds_wave_base, int lane) {
#ifdef HAVE_GLL
  __builtin_amdgcn_global_load_lds(
      (const __attribute__((address_space(1))) void*)g,
      (__attribute__((address_space(3))) void*)lds_wave_base, 16, 0, 0);
#else
  *(uint4*)(lds_wave_base + lane * 8) = *(const uint4*)g;
#endif
}

// ---- K2: sim = X @ X^T, upper-tri 128x128 tiles, BK=64, 2-phase dbuf -------
// EXACT R3 kernel (measured 66us, 0 bank conflicts). Do not touch.
__global__ __launch_bounds__(256) void simgemm_kernel(
    const uint16_t* __restrict__ X, const int* __restrict__ labels,
    float* __restrict__ C, uint32_t* __restrict__ gmin, uint32_t* __restrict__ gmax,
    int B, int D) {
  __shared__ __align__(16) uint16_t sT[2][2][128 * 64];
  __shared__ int slabR[128];
  __shared__ int slabC[128];

  const int nblk = B >> 7;
  const int nb   = nblk * (nblk + 1) / 2;

  int t = blockIdx.x;
  if ((nb & 7) == 0) {
    const int cpx = nb >> 3;
    t = (t % 8) * cpx + t / 8;
  }
  int bi = 0;
  while (t >= nblk - bi) { t -= nblk - bi; ++bi; }
  const int bj = bi + t;
  const int bm = bi * 128;
  const int bn = bj * 128;

  const int tid  = threadIdx.x;
  const int wave = tid >> 6;
  const int lane = tid & 63;
  const int waveM = wave >> 1, waveN = wave & 1;

  if (tid < 128) slabR[tid] = labels[bm + tid];
  else           slabC[tid - 128] = labels[bn + tid - 128];

  const uint16_t* gA = X + (size_t)bm * D;
  const uint16_t* gB = X + (size_t)bn * D;

  int srcOff[4];
#pragma unroll
  for (int s = 0; s < 4; ++s) {
    const int idx = s * 256 + tid;
    const int row = idx >> 3;
    const int cb  = ((idx & 7) << 4) ^ ((row & 7) << 4);
    srcOff[s] = row * D + (cb >> 1);
  }

  const int fr = lane & 15;
  const int fq = lane >> 4;
  const int sw = (fr & 7) << 4;

  f32x4 acc[4][4] = {};

  const int NT = D >> 6;

#pragma unroll
  for (int s = 0; s < 4; ++s) {
    uint16_t* dA = &sT[0][0][0] + (s * 256 + wave * 64) * 8;
    uint16_t* dB = &sT[0][1][0] + (s * 256 + wave * 64) * 8;
    stage16(gA + srcOff[s], dA, lane);
    stage16(gB + srcOff[s], dB, lane);
  }
  __syncthreads();

  int cur = 0;
  for (int kt = 0; kt < NT; ++kt) {
    if (kt + 1 < NT) {
      const int k0 = (kt + 1) << 6;
#pragma unroll
      for (int s = 0; s < 4; ++s) {
        uint16_t* dA = &sT[cur ^ 1][0][0] + (s * 256 + wave * 64) * 8;
        uint16_t* dB = &sT[cur ^ 1][1][0] + (s * 256 + wave * 64) * 8;
        stage16(gA + srcOff[s] + k0, dA, lane);
        stage16(gB + srcOff[s] + k0, dB, lane);
      }
    }

    const char* tA = (const char*)&sT[cur][0][0];
    const char* tB = (const char*)&sT[cur][1][0];
#pragma unroll
    for (int kk = 0; kk < 2; ++kk) {
      const int cbyte = (kk * 64 + fq * 16) ^ sw;
      bf16x8 af[4], bfv[4];
#pragma unroll
      for (int mt = 0; mt < 4; ++mt) {
        const int rowa = waveM * 64 + mt * 16 + fr;
        af[mt] = *(const bf16x8*)(tA + rowa * 128 + cbyte);
      }
#pragma unroll
      for (int nt = 0; nt < 4; ++nt) {
        const int rowb = waveN * 64 + nt * 16 + fr;
        bfv[nt] = *(const bf16x8*)(tB + rowb * 128 + cbyte);
      }
#pragma unroll
      for (int mt = 0; mt < 4; ++mt)
#pragma unroll
        for (int nt = 0; nt < 4; ++nt)
          acc[mt][nt] = __builtin_amdgcn_mfma_f32_16x16x32_bf16(
              af[mt], bfv[nt], acc[mt][nt], 0, 0, 0);
    }

    __syncthreads();
    cur ^= 1;
  }

  // direct write
#pragma unroll
  for (int mt = 0; mt < 4; ++mt) {
#pragma unroll
    for (int nt = 0; nt < 4; ++nt) {
      const int col = bn + waveN * 64 + nt * 16 + fr;
#pragma unroll
      for (int r = 0; r < 4; ++r) {
        const int row = bm + waveM * 64 + mt * 16 + fq * 4 + r;
        C[(size_t)row * B + col] = acc[mt][nt][r];
      }
    }
  }

  // mirror write
  if (bi != bj) {
#pragma unroll
    for (int mt = 0; mt < 4; ++mt) {
#pragma unroll
      for (int nt = 0; nt < 4; ++nt) {
        const int col  = bn + waveN * 64 + nt * 16 + fr;
        const int rowb = bm + waveM * 64 + mt * 16 + fq * 4;
        *(f32x4*)(C + (size_t)col * B + rowb) = acc[mt][nt];
      }
    }
  }

  const float INF = __builtin_inff();

  int lr[4][4];
#pragma unroll
  for (int mt = 0; mt < 4; ++mt)
#pragma unroll
    for (int r = 0; r < 4; ++r)
      lr[mt][r] = slabR[waveM * 64 + mt * 16 + fq * 4 + r];
  int lc[4];
#pragma unroll
  for (int nt = 0; nt < 4; ++nt) lc[nt] = slabC[waveN * 64 + nt * 16 + fr];

  // row-side stats
  {
    float rmin[4][4], rmax[4][4];
#pragma unroll
    for (int mt = 0; mt < 4; ++mt)
#pragma unroll
      for (int r = 0; r < 4; ++r) { rmin[mt][r] = INF; rmax[mt][r] = -INF; }

#pragma unroll
    for (int mt = 0; mt < 4; ++mt) {
#pragma unroll
      for (int nt = 0; nt < 4; ++nt) {
        const int gcol = bn + waveN * 64 + nt * 16 + fr;
#pragma unroll
        for (int r = 0; r < 4; ++r) {
          const int grow = bm + waveM * 64 + mt * 16 + fq * 4 + r;
          const float s = acc[mt][nt][r];
          if (lr[mt][r] == lc[nt]) {
            if (grow != gcol && s < POS_CAP) rmin[mt][r] = fminf(rmin[mt][r], s);
          } else {
            rmax[mt][r] = fmaxf(rmax[mt][r], s);
          }
        }
      }
    }
#pragma unroll
    for (int mt = 0; mt < 4; ++mt)
#pragma unroll
      for (int r = 0; r < 4; ++r) {
#pragma unroll
        for (int m = 1; m < 16; m <<= 1) {
          rmin[mt][r] = fminf(rmin[mt][r], __shfl_xor(rmin[mt][r], m, 64));
          rmax[mt][r] = fmaxf(rmax[mt][r], __shfl_xor(rmax[mt][r], m, 64));
        }
      }
    if (fr == 0) {
#pragma unroll
      for (int mt = 0; mt < 4; ++mt)
#pragma unroll
        for (int r = 0; r < 4; ++r) {
          const int grow = bm + waveM * 64 + mt * 16 + fq * 4 + r;
          if (rmin[mt][r] < INF)  atomicMin(&gmin[grow], fenc(rmin[mt][r]));
          if (rmax[mt][r] > -INF) atomicMax(&gmax[grow], fenc(rmax[mt][r]));
        }
    }
  }

  // col-side stats (mirrored tile)
  if (bi != bj) {
    float cmin[4], cmax[4];
#pragma unroll
    for (int nt = 0; nt < 4; ++nt) { cmin[nt] = INF; cmax[nt] = -INF; }
#pragma unroll
    for (int nt = 0; nt < 4; ++nt) {
      const int gcol = bn + waveN * 64 + nt * 16 + fr;
#pragma unroll
      for (int mt = 0; mt < 4; ++mt) {
#pragma unroll
        for (int r = 0; r < 4; ++r) {
          const int grow = bm + waveM * 64 + mt * 16 + fq * 4 + r;
          const float s = acc[mt][nt][r];
          if (lc[nt] == lr[mt][r]) {
            if (grow != gcol && s < POS_CAP) cmin[nt] = fminf(cmin[nt], s);
          } else {
            cmax[nt] = fmaxf(cmax[nt], s);
          }
        }
      }
    }
#pragma unroll
    for (int nt = 0; nt < 4; ++nt) {
#pragma unroll
      for (int m = 16; m < 64; m <<= 1) {
        cmin[nt] = fminf(cmin[nt], __shfl_xor(cmin[nt], m, 64));
        cmax[nt] = fmaxf(cmax[nt], __shfl_xor(cmax[nt], m, 64));
      }
    }
    if (fq == 0) {
#pragma unroll
      for (int nt = 0; nt < 4; ++nt) {
        const int gcol = bn + waveN * 64 + nt * 16 + fr;
        if (cmin[nt] < INF)  atomicMin(&gmin[gcol], fenc(cmin[nt]));
        if (cmax[nt] > -INF) atomicMax(&gmax[gcol], fenc(cmax[nt]));
      }
    }
  }
}

// ---- K3: rowloss, 2 rows/block, sim+labels gll dbuf, fused final reduce ----
__device__ __forceinline__ void proc4p(
    const float4 v, const int4 lb, int jbase, int i, int li,
    float minpos, float maxneg, float& ps, float& ns) {
  const float s4[4] = {v.x, v.y, v.z, v.w};
  const int   l4[4] = {lb.x, lb.y, lb.z, lb.w};
#pragma unroll
  for (int q = 0; q < 4; ++q) {
    const int jj = jbase + q;
    const float s = s4[q];
    const bool same = (l4[q] == li);
    const bool pk = same && (jj != i) && (s < POS_CAP) && (s - MARGIN < maxneg);
    const bool nk = (!same) && (s + MARGIN > minpos);
    const float ep = __expf(-SCALE_POS * (s - THRESH));
    const float en = __expf( SCALE_NEG * (s - THRESH));
    ps += pk ? ep : 0.f;
    ns += nk ? en : 0.f;
  }
}

__global__ __launch_bounds__(256) void rowloss_kernel(
    const float* __restrict__ sim, const int* __restrict__ labels,
    const uint32_t* __restrict__ gmin, const uint32_t* __restrict__ gmax,
    float* __restrict__ rowbuf, float* __restrict__ out,
    uint32_t* __restrict__ cnt, int B) {
  // sim dbuf [2][2 rows][1024 f32] = 16 KiB, labels dbuf [2][1024 i32] = 8 KiB
  __shared__ __align__(16) float sbuf[2][2][1024];
  __shared__ __align__(16) int   slb[2][1024];
  __shared__ float red[4][4];
  __shared__ float fred[4];
  __shared__ int   isLast;

  const int tid  = threadIdx.x;
  const int wave = tid >> 6;
  const int lane = tid & 63;
  const float INF = __builtin_inff();

  const int i0 = blockIdx.x * 2;
  const int li0 = labels[i0];
  const int li1 = labels[i0 + 1];

  const uint32_t km0 = gmin[i0],     kx0 = gmax[i0];
  const uint32_t km1 = gmin[i0 + 1], kx1 = gmax[i0 + 1];
  const bool hp0 = (km0 != 0xFFFFFFFFu), hn0 = (kx0 != 0u);
  const bool hp1 = (km1 != 0xFFFFFFFFu), hn1 = (kx1 != 0u);
  const float mp0 = hp0 ? fdec(km0) : INF,  mx0 = hn0 ? fdec(kx0) : -INF;
  const float mp1 = hp1 ? fdec(km1) : INF,  mx1 = hn1 ? fdec(kx1) : -INF;

  const float* row0 = sim + (size_t)i0 * B;
  const float* row1 = row0 + B;

  const int NC = B >> 10;        // 1024-col chunks (4 for B=4096)

  // prologue: stage chunk 0 (2 sim rows + labels) into buf 0.
  // gll dest = wave-uniform base + lane*16; src per-lane.
  {
    const int jw = wave * 256 + lane * 4;   // this lane's 4-elem slot
    stage16((const uint16_t*)(row0 + jw),        (uint16_t*)&sbuf[0][0][wave * 256], lane);
    stage16((const uint16_t*)(row1 + jw),        (uint16_t*)&sbuf[0][1][wave * 256], lane);
    stage16((const uint16_t*)(labels + jw),      (uint16_t*)&slb[0][wave * 256],     lane);
  }

  float ps0 = 0.f, ns0 = 0.f, ps1 = 0.f, ns1 = 0.f;
  int buf = 0;
  for (int c = 0; c < NC; ++c) {
    __syncthreads();             // drains chunk-c glls (issued last iter)
    if (c + 1 < NC) {            // prefetch c+1; NOTHING in this iteration
      const int jn = ((c + 1) << 10) + wave * 256 + lane * 4;
      stage16((const uint16_t*)(row0 + jn),   (uint16_t*)&sbuf[buf ^ 1][0][wave * 256], lane);
      stage16((const uint16_t*)(row1 + jn),   (uint16_t*)&sbuf[buf ^ 1][1][wave * 256], lane);
      stage16((const uint16_t*)(labels + jn), (uint16_t*)&slb[buf ^ 1][wave * 256],     lane);
    }
    // loop body has ZERO non-gll vmem: only ds_read (lgkmcnt) below.
    const int jb = (c << 10) + tid * 4;
    const int4   lb = *(const int4*)(&slb[buf][tid * 4]);
    const float4 v0 = *(const float4*)(&sbuf[buf][0][tid * 4]);
    const float4 v1 = *(const float4*)(&sbuf[buf][1][tid * 4]);
    proc4p(v0, lb, jb, i0,     li0, mp0, mx0, ps0, ns0);
    proc4p(v1, lb, jb, i0 + 1, li1, mp1, mx1, ps1, ns1);
    buf ^= 1;
  }

#pragma unroll
  for (int m = 32; m > 0; m >>= 1) {
    ps0 += __shfl_xor(ps0, m, 64);
    ns0 += __shfl_xor(ns0, m, 64);
    ps1 += __shfl_xor(ps1, m, 64);
    ns1 += __shfl_xor(ns1, m, 64);
  }
  if (lane == 0) {
    red[wave][0] = ps0; red[wave][1] = ns0;
    red[wave][2] = ps1; red[wave][3] = ns1;
  }
  __syncthreads();

  if (tid < 2) {
    const int r = tid;
    const float P = red[0][r * 2] + red[1][r * 2] + red[2][r * 2] + red[3][r * 2];
    const float N = red[0][r * 2 + 1] + red[1][r * 2 + 1] + red[2][r * 2 + 1] + red[3][r * 2 + 1];
    const bool hp = r ? hp1 : hp0;
    const bool hn = r ? hn1 : hn0;
    const bool has_row = hp && hn && (P > 0.f) && (N > 0.f);
    rowbuf[i0 + r] = has_row
        ? (log1pf(P) * (1.0f / SCALE_POS) + log1pf(N) * (1.0f / SCALE_NEG))
        : 0.f;
  }
  __threadfence();
  __syncthreads();

  if (tid == 0) {
    const uint32_t v = atomicAdd(cnt, 1u);
    isLast = (v == (uint32_t)(gridDim.x - 1)) ? 1 : 0;
  }
  __syncthreads();

  if (isLast) {
    __threadfence();
    float s = 0.f;
    for (int j = tid * 4; j < B; j += 1024) {
      float4 v = *(const float4*)(rowbuf + j);
      s += v.x + v.y + v.z + v.w;
    }
#pragma unroll
    for (int m = 32; m > 0; m >>= 1) s += __shfl_xor(s, m, 64);
    if (lane == 0) fred[wave] = s;
    __syncthreads();
    if (tid == 0)
      out[0] = (fred[0] + fred[1] + fred[2] + fred[3]) * (1.0f / (float)B);
  }
}

// ---------------------------------------------------------------------------
extern "C" void kernel_launch(void* const* d_in, const int* in_sizes, int n_in,
                              void* d_out, int out_size, void* d_ws, size_t ws_size,
                              hipStream_t stream) {
  const float* x      = (const float*)d_in[0];
  const int*   labels = (const int*)d_in[1];
  float*       out    = (float*)d_out;

  const int B = in_sizes[1];           // 4096
  const int D = in_sizes[0] / B;       // 1024

  char* ws = (char*)d_ws;
  uint16_t* xbf = (uint16_t*)ws;       ws += (((size_t)B * D * 2) + 255) & ~(size_t)255;
  float* sim = (float*)ws;             ws += (size_t)B * B * 4;
  uint32_t* gmin = (uint32_t*)ws;      ws += (size_t)B * 4;
  uint32_t* gmax = (uint32_t*)ws;      ws += (size_t)B * 4;
  float* rowbuf = (float*)ws;          ws += (size_t)B * 4;
  uint32_t* cnt = (uint32_t*)ws;       ws += 256;

  const int n = B * D;
  cvt_bf16_kernel<<<n / 1024, 256, 0, stream>>>(x, xbf, n, gmin, gmax, cnt, B);

  const int nblk = B / 128;
  const int nb   = nblk * (nblk + 1) / 2;   // 528 upper-triangle tiles
  simgemm_kernel<<<nb, 256, 0, stream>>>(xbf, labels, sim, gmin, gmax, B, D);

  rowloss_kernel<<<B / 2, 256, 0, stream>>>(sim, labels, gmin, gmax,
                                            rowbuf, out, cnt, B);
}

// Round 10
// 209.290 us; speedup vs baseline: 2.6967x; 1.3100x over previous
//
#include <hip/hip_runtime.h>
#include <hip/hip_bf16.h>
#include <math.h>
#include <stdint.h>

// ---------------------------------------------------------------------------
// MultiSimilarityLoss on MI355X.
//   x: [B=4096, D=1024] fp32 (L2-normalized rows), labels: [B] int32
//   out: scalar fp32 = mean of mined multi-similarity loss
// Pipeline (R10) -- 3 dispatches:
//   K1: cvt fp32->bf16, fused gmin/gmax/cnt init (block 0)
//   K2: sim = x @ x^T, FULL SQUARE 1024-block grid (4 blocks/CU supplied
//       AND resident: 33KB LDS, no reg cap), BK=32 pipelined dbuf, T2
//       swizzle, direct write + row-side stats only. (= R7 GEMM, which was
//       never fairly measured -- R7's profile was destroyed by a spilling
//       rowloss. This round isolates it next to known-good kernels.)
//   K3: rowloss = R6's best-measured kernel (77us) with labels read from
//       LDS as int4 (R6's 393K conflict cycles came from scalar slab
//       reads); fused last-block final reduce.
// R9 post-mortem: zero-vmem-in-loop didn't help (161us) -> serialization
//   theory dead. Cross-round insight: every kernel at 2 blocks/CU is ~10x
//   slower per-iteration than m97's identical loop at 3-4 blocks/CU.
//   Occupancy (blocks/CU) is the last untested lever; R10 measures it.
// ---------------------------------------------------------------------------

#define THRESH    0.5f
#define MARGIN    0.1f
#define SCALE_POS 2.0f
#define SCALE_NEG 40.0f
#define POS_CAP   (1.0f - 1e-5f)

typedef __bf16 bf16x8 __attribute__((ext_vector_type(8)));
typedef float  f32x4  __attribute__((ext_vector_type(4)));

__device__ __forceinline__ uint16_t f2bf(float f) {
  union { float f; uint32_t u; } v; v.f = f;
  uint32_t u = v.u;
  u += 0x7FFFu + ((u >> 16) & 1u);
  return (uint16_t)(u >> 16);
}

__device__ __forceinline__ uint32_t fenc(float f) {
  union { float f; uint32_t u; } v; v.f = f;
  return (v.u & 0x80000000u) ? ~v.u : (v.u ^ 0x80000000u);
}
__device__ __forceinline__ float fdec(uint32_t k) {
  union { float f; uint32_t u; } v;
  v.u = (k & 0x80000000u) ? (k ^ 0x80000000u) : ~k;
  return v.f;
}

// ---- K1: cvt + stat/counter init -------------------------------------------
__global__ __launch_bounds__(256) void cvt_bf16_kernel(
    const float* __restrict__ x, uint16_t* __restrict__ y, int n,
    uint32_t* __restrict__ gmin, uint32_t* __restrict__ gmax,
    uint32_t* __restrict__ cnt, int B) {
  const int tid = threadIdx.x;
  int i = (blockIdx.x * 256 + tid) * 4;
  if (i + 3 < n) {
    float4 v = *(const float4*)(x + i);
    ushort4 o;
    o.x = f2bf(v.x); o.y = f2bf(v.y); o.z = f2bf(v.z); o.w = f2bf(v.w);
    *(ushort4*)(y + i) = o;
  }
  if (blockIdx.x == 0) {
    for (int j = tid; j < B; j += 256) {
      gmin[j] = 0xFFFFFFFFu;
      gmax[j] = 0u;
    }
    if (tid == 0) *cnt = 0u;
  }
}

#if defined(__has_builtin)
#if __has_builtin(__builtin_amdgcn_global_load_lds)
#define HAVE_GLL 1
#endif
#endif

__device__ __forceinline__ void stage16(const uint16_t* g, uint16_t* lds_wave_base, int lane) {
#ifdef HAVE_GLL
  __builtin_amdgcn_global_load_lds(
      (const __attribute__((address_space(1))) void*)g,
      (__attribute__((address_space(3))) void*)lds_wave_base, 16, 0, 0);
#else
  *(uint4*)(lds_wave_base + lane * 8) = *(const uint4*)g;
#endif
}

// ---- K2: sim = X @ X^T, square grid (4 blocks/CU), BK=32 pipelined dbuf ----
__global__ __launch_bounds__(256) void simgemm_kernel(
    const uint16_t* __restrict__ X, const int* __restrict__ labels,
    float* __restrict__ C, uint32_t* __restrict__ gmin, uint32_t* __restrict__ gmax,
    int B, int D) {
  // [buf][A=0/B=1][128 rows][32 cols] bf16 = 32 KiB; + 1 KiB labels
  __shared__ __align__(16) uint16_t sT[2][2][128 * 32];
  __shared__ int slabR[128];
  __shared__ int slabC[128];

  const int nblk = B >> 7;            // 32
  const int nb   = nblk * nblk;       // 1024

  // XCD chunk swizzle: orig b lands on XCD b%8; map b -> t so each XCD's
  // blocks get contiguous tile indices (shared A-panels -> L2 locality).
  int t = blockIdx.x;
  { const int cpx = nb >> 3; t = (t & 7) * cpx + (t >> 3); }
  const int bi = t / nblk;
  const int bj = t - bi * nblk;
  const int bm = bi * 128;
  const int bn = bj * 128;

  const int tid  = threadIdx.x;
  const int wave = tid >> 6;
  const int lane = tid & 63;
  const int waveM = wave >> 1, waveN = wave & 1;

  if (tid < 128) slabR[tid] = labels[bm + tid];
  else           slabC[tid - 128] = labels[bn + tid - 128];

  const uint16_t* gA = X + (size_t)bm * D;
  const uint16_t* gB = X + (size_t)bn * D;

  // staging map: 16B-chunk idx = s*256 + tid (s=0,1); row = idx>>2 (64B rows)
  // inverse-swizzled global byte-in-row = ((idx&3)<<4) ^ ((row&3)<<4)
  int srcOff[2];
#pragma unroll
  for (int s = 0; s < 2; ++s) {
    const int idx = s * 256 + tid;
    const int row = idx >> 2;
    const int cb  = ((idx & 3) << 4) ^ ((row & 3) << 4);
    srcOff[s] = row * D + (cb >> 1);
  }

  const int fr = lane & 15;
  const int fq = lane >> 4;
  const int sw = (fr & 3) << 4;   // read swizzle (row&3 == fr&3)

  f32x4 acc[4][4] = {};

  const int NT = D >> 5;          // 32 K-tiles of 32

  // prologue: stage tile 0 into buf 0
#pragma unroll
  for (int s = 0; s < 2; ++s) {
    uint16_t* dA = &sT[0][0][0] + (s * 256 + wave * 64) * 8;
    uint16_t* dB = &sT[0][1][0] + (s * 256 + wave * 64) * 8;
    stage16(gA + srcOff[s], dA, lane);
    stage16(gB + srcOff[s], dB, lane);
  }
  __syncthreads();

  int cur = 0;
  for (int kt = 0; kt < NT; ++kt) {
    if (kt + 1 < NT) {
      const int k0 = (kt + 1) << 5;
#pragma unroll
      for (int s = 0; s < 2; ++s) {
        uint16_t* dA = &sT[cur ^ 1][0][0] + (s * 256 + wave * 64) * 8;
        uint16_t* dB = &sT[cur ^ 1][1][0] + (s * 256 + wave * 64) * 8;
        stage16(gA + srcOff[s] + k0, dA, lane);
        stage16(gB + srcOff[s] + k0, dB, lane);
      }
    }

    const char* tA = (const char*)&sT[cur][0][0];
    const char* tB = (const char*)&sT[cur][1][0];
    const int cbyte = (fq * 16) ^ sw;
    bf16x8 af[4], bfv[4];
#pragma unroll
    for (int mt = 0; mt < 4; ++mt) {
      const int rowa = waveM * 64 + mt * 16 + fr;
      af[mt] = *(const bf16x8*)(tA + rowa * 64 + cbyte);
    }
#pragma unroll
    for (int nt = 0; nt < 4; ++nt) {
      const int rowb = waveN * 64 + nt * 16 + fr;
      bfv[nt] = *(const bf16x8*)(tB + rowb * 64 + cbyte);
    }
#pragma unroll
    for (int mt = 0; mt < 4; ++mt)
#pragma unroll
      for (int nt = 0; nt < 4; ++nt)
        acc[mt][nt] = __builtin_amdgcn_mfma_f32_16x16x32_bf16(
            af[mt], bfv[nt], acc[mt][nt], 0, 0, 0);

    __syncthreads();
    cur ^= 1;
  }

  // ---- direct write (square grid covers all (i,j)) ------------------------
#pragma unroll
  for (int mt = 0; mt < 4; ++mt) {
#pragma unroll
    for (int nt = 0; nt < 4; ++nt) {
      const int col = bn + waveN * 64 + nt * 16 + fr;
#pragma unroll
      for (int r = 0; r < 4; ++r) {
        const int row = bm + waveM * 64 + mt * 16 + fq * 4 + r;
        C[(size_t)row * B + col] = acc[mt][nt][r];
      }
    }
  }

  // ---- per-row stats (row-side only; full grid covers all pairs) ----------
  const float INF = __builtin_inff();

  int lr[4][4];
#pragma unroll
  for (int mt = 0; mt < 4; ++mt)
#pragma unroll
    for (int r = 0; r < 4; ++r)
      lr[mt][r] = slabR[waveM * 64 + mt * 16 + fq * 4 + r];
  int lc[4];
#pragma unroll
  for (int nt = 0; nt < 4; ++nt) lc[nt] = slabC[waveN * 64 + nt * 16 + fr];

  float rmin[4][4], rmax[4][4];
#pragma unroll
  for (int mt = 0; mt < 4; ++mt)
#pragma unroll
    for (int r = 0; r < 4; ++r) { rmin[mt][r] = INF; rmax[mt][r] = -INF; }

#pragma unroll
  for (int mt = 0; mt < 4; ++mt) {
#pragma unroll
    for (int nt = 0; nt < 4; ++nt) {
      const int gcol = bn + waveN * 64 + nt * 16 + fr;
#pragma unroll
      for (int r = 0; r < 4; ++r) {
        const int grow = bm + waveM * 64 + mt * 16 + fq * 4 + r;
        const float s = acc[mt][nt][r];
        if (lr[mt][r] == lc[nt]) {
          if (grow != gcol && s < POS_CAP) rmin[mt][r] = fminf(rmin[mt][r], s);
        } else {
          rmax[mt][r] = fmaxf(rmax[mt][r], s);
        }
      }
    }
  }
#pragma unroll
  for (int mt = 0; mt < 4; ++mt)
#pragma unroll
    for (int r = 0; r < 4; ++r) {
#pragma unroll
      for (int m = 1; m < 16; m <<= 1) {
        rmin[mt][r] = fminf(rmin[mt][r], __shfl_xor(rmin[mt][r], m, 64));
        rmax[mt][r] = fmaxf(rmax[mt][r], __shfl_xor(rmax[mt][r], m, 64));
      }
    }
  if (fr == 0) {
#pragma unroll
    for (int mt = 0; mt < 4; ++mt)
#pragma unroll
      for (int r = 0; r < 4; ++r) {
        const int grow = bm + waveM * 64 + mt * 16 + fq * 4 + r;
        if (rmin[mt][r] < INF)  atomicMin(&gmin[grow], fenc(rmin[mt][r]));
        if (rmax[mt][r] > -INF) atomicMax(&gmax[grow], fenc(rmax[mt][r]));
      }
  }
}

// ---- K3: rowloss = R6 (77us) + int4 slab reads + fused final reduce --------
__global__ __launch_bounds__(256) void rowloss_kernel(
    const float* __restrict__ sim, const int* __restrict__ labels,
    const uint32_t* __restrict__ gmin, const uint32_t* __restrict__ gmax,
    float* __restrict__ rowbuf, float* __restrict__ out,
    uint32_t* __restrict__ cnt, int B) {
  __shared__ int   slab[4096];
  __shared__ float red[4][8];
  __shared__ float fred[4];
  __shared__ int   isLast;

  const int tid  = threadIdx.x;
  const int wave = tid >> 6;
  const int lane = tid & 63;
  const float INF = __builtin_inff();

  for (int tq = tid; tq < (B >> 2); tq += 256)
    ((int4*)slab)[tq] = ((const int4*)labels)[tq];
  __syncthreads();

  const int i0 = blockIdx.x * 4;

  float minpos[4], maxneg[4];
  bool  haspos[4], hasneg[4];
  int   li[4];
#pragma unroll
  for (int r = 0; r < 4; ++r) {
    const uint32_t km = gmin[i0 + r], kx = gmax[i0 + r];
    haspos[r] = (km != 0xFFFFFFFFu);
    hasneg[r] = (kx != 0u);
    minpos[r] = haspos[r] ? fdec(km) : INF;
    maxneg[r] = hasneg[r] ? fdec(kx) : -INF;
    li[r] = slab[i0 + r];
  }

  float ps[4] = {}, ns[4] = {};
  const int iters = B >> 10;   // 4 col-chunks of 1024
  for (int it = 0; it < iters; ++it) {
    const int j = it * 1024 + tid * 4;
    float4 v[4];
#pragma unroll
    for (int r = 0; r < 4; ++r)    // 4 independent loads
      v[r] = *(const float4*)(sim + (size_t)(i0 + r) * B + j);
    // one int4 LDS read (conflict-free b128) instead of 16 scalar reads
    const int4 lb = *(const int4*)(&slab[j]);
    const int l4[4] = {lb.x, lb.y, lb.z, lb.w};
#pragma unroll
    for (int r = 0; r < 4; ++r) {
      const int i = i0 + r;
      float s4[4] = {v[r].x, v[r].y, v[r].z, v[r].w};
#pragma unroll
      for (int q = 0; q < 4; ++q) {
        const int jj = j + q;
        const float s = s4[q];
        if (l4[q] == li[r]) {
          if (jj != i && s < POS_CAP && (s - MARGIN < maxneg[r]))
            ps[r] += __expf(-SCALE_POS * (s - THRESH));
        } else {
          if (s + MARGIN > minpos[r])
            ns[r] += __expf(SCALE_NEG * (s - THRESH));
        }
      }
    }
  }

#pragma unroll
  for (int r = 0; r < 4; ++r) {
#pragma unroll
    for (int m = 32; m > 0; m >>= 1) {
      ps[r] += __shfl_xor(ps[r], m, 64);
      ns[r] += __shfl_xor(ns[r], m, 64);
    }
  }
  if (lane == 0) {
#pragma unroll
    for (int r = 0; r < 4; ++r) { red[wave][r] = ps[r]; red[wave][4 + r] = ns[r]; }
  }
  __syncthreads();

  if (tid < 4) {   // one thread per row: combine waves in fixed order
    const int r = tid;
    const float P = red[0][r] + red[1][r] + red[2][r] + red[3][r];
    const float N = red[0][4 + r] + red[1][4 + r] + red[2][4 + r] + red[3][4 + r];
    const bool has_row = haspos[r] && hasneg[r] && (P > 0.f) && (N > 0.f);
    rowbuf[i0 + r] = has_row
        ? (log1pf(P) * (1.0f / SCALE_POS) + log1pf(N) * (1.0f / SCALE_NEG))
        : 0.f;
  }
  __threadfence();
  __syncthreads();

  if (tid == 0) {
    const uint32_t v = atomicAdd(cnt, 1u);
    isLast = (v == (uint32_t)(gridDim.x - 1)) ? 1 : 0;
  }
  __syncthreads();

  if (isLast) {
    __threadfence();
    float s = 0.f;
    for (int j = tid * 4; j < B; j += 1024) {
      float4 v = *(const float4*)(rowbuf + j);
      s += v.x + v.y + v.z + v.w;
    }
#pragma unroll
    for (int m = 32; m > 0; m >>= 1) s += __shfl_xor(s, m, 64);
    if (lane == 0) fred[wave] = s;
    __syncthreads();
    if (tid == 0)
      out[0] = (fred[0] + fred[1] + fred[2] + fred[3]) * (1.0f / (float)B);
  }
}

// ---------------------------------------------------------------------------
extern "C" void kernel_launch(void* const* d_in, const int* in_sizes, int n_in,
                              void* d_out, int out_size, void* d_ws, size_t ws_size,
                              hipStream_t stream) {
  const float* x      = (const float*)d_in[0];
  const int*   labels = (const int*)d_in[1];
  float*       out    = (float*)d_out;

  const int B = in_sizes[1];           // 4096
  const int D = in_sizes[0] / B;       // 1024

  char* ws = (char*)d_ws;
  uint16_t* xbf = (uint16_t*)ws;       ws += (((size_t)B * D * 2) + 255) & ~(size_t)255;
  float* sim = (float*)ws;             ws += (size_t)B * B * 4;
  uint32_t* gmin = (uint32_t*)ws;      ws += (size_t)B * 4;
  uint32_t* gmax = (uint32_t*)ws;      ws += (size_t)B * 4;
  float* rowbuf = (float*)ws;          ws += (size_t)B * 4;
  uint32_t* cnt = (uint32_t*)ws;       ws += 256;

  const int n = B * D;
  cvt_bf16_kernel<<<n / 1024, 256, 0, stream>>>(x, xbf, n, gmin, gmax, cnt, B);

  const int nblk = B / 128;
  const int nb   = nblk * nblk;        // 1024 square tiles = 4 blocks/CU
  simgemm_kernel<<<nb, 256, 0, stream>>>(xbf, labels, sim, gmin, gmax, B, D);

  rowloss_kernel<<<B / 4, 256, 0, stream>>>(sim, labels, gmin, gmax,
                                            rowbuf, out, cnt, B);
}